// Round 5
// baseline (614.761 us; speedup 1.0000x reference)
//
#include <hip/hip_runtime.h>
#include <hip/hip_bf16.h>

// One-hot expansion: mask [1,1,256,256,48] fp32 labels in 0..40 ->
// out [1,40,256,256,48] fp32, out[n,v] = (mask[v] == n+1).
//
// R1: 1 store stream/wave, 40x mask re-read -> 474 us total (best).
// R2: nt stores -> neutral. R4: G=8 planes/block -> 491. R5: reg-resident
//     mask, 40 sequential bursts -> 490. Read-traffic cuts always refunded.
//
// R6 = DIAGNOSTIC (intentional ~790 us): two stories fit all data and only
// our dispatch's counters discriminate, but it never makes the top-5 table
// (fills at ~318 us dominate). So: replicate R1's exact per-block pattern
// x3 via gridDim.z (passes dispatch in z-order, time-separated >> L2
// turnover -> each pass pays full HBM traffic; identical writes keep
// correctness). Dispatch ~470 us -> top-5 -> read its counters.
//   Story A (mask re-reads miss): FETCH ~ 1.5 GB, R1 was at 6.4 TB/s
//            roofline -> next: shrink re-read traffic (u8 mask).
//   Story B (mask re-reads hit): FETCH ~ 40 MB, write path capped at
//            ~3.3 TB/s -> next: streaming stores / fill-style structure.

constexpr int V = 256 * 256 * 48;   // 3,145,728 voxels per plane
constexpr int N_LABELS = 40;
constexpr int REPEAT = 3;           // diagnostic passes (z-dim)

typedef float f32x4 __attribute__((ext_vector_type(4)));

__global__ __launch_bounds__(256)
void onehot_kernel(const float* __restrict__ mask, float* __restrict__ out) {
    const int i = (blockIdx.x * blockDim.x + threadIdx.x) * 4;  // voxel index
    const int n = blockIdx.y;                                   // label plane
    const float lab = (float)(n + 1);

    const f32x4 m = *reinterpret_cast<const f32x4*>(mask + i);

    f32x4 o;
    o.x = (m.x == lab) ? 1.0f : 0.0f;
    o.y = (m.y == lab) ? 1.0f : 0.0f;
    o.z = (m.z == lab) ? 1.0f : 0.0f;
    o.w = (m.w == lab) ? 1.0f : 0.0f;

    *reinterpret_cast<f32x4*>(out + (size_t)n * V + i) = o;
}

extern "C" void kernel_launch(void* const* d_in, const int* in_sizes, int n_in,
                              void* d_out, int out_size, void* d_ws, size_t ws_size,
                              hipStream_t stream) {
    const float* mask = (const float*)d_in[0];
    float* out = (float*)d_out;

    const int threads = 256;
    const int blocks_x = (V / 4) / threads;  // 3,072 chunks per plane
    dim3 grid(blocks_x, N_LABELS, REPEAT);   // 3 identical passes (diagnostic)

    onehot_kernel<<<grid, threads, 0, stream>>>(mask, out);
}